// Round 1
// baseline (463.789 us; speedup 1.0000x reference)
//
#include <hip/hip_runtime.h>
#include <math.h>

#define ROW_N 512
#define N_ITERS 100
#define LAMBDA 10.0f

// Precompute FISTA momentum coefficients coef[k] = (t_k - 1) / t_{k+1},
// t_0 = 1, t_{k+1} = (1 + sqrt(1 + 4 t_k^2)) / 2. Input-independent.
__global__ void coef_kernel(float* __restrict__ coefs) {
    if (threadIdx.x == 0) {
        float t = 1.0f;
        for (int k = 0; k < N_ITERS; ++k) {
            float t_new = 0.5f * (1.0f + sqrtf(1.0f + 4.0f * t * t));
            coefs[k] = (t - 1.0f) / t_new;
            t = t_new;
        }
    }
}

// One wave (64 lanes) per row of 512; 8 contiguous elements per lane.
// All FISTA state in registers; halo exchange via 4 shuffles per iteration.
template <bool USE_TABLE>
__global__ __launch_bounds__(256) void fista_kernel(
    const float* __restrict__ in, float* __restrict__ out,
    const float* __restrict__ coefs, int n_rows)
{
    const int wid  = (int)((blockIdx.x * 256u + threadIdx.x) >> 6);
    const int lane = (int)(threadIdx.x & 63u);
    if (wid >= n_rows) return;

    const float* row = in + (size_t)wid * ROW_N;

    float y[8], ay[8], x[8], z[8];
    {
        const float4 v0 = *(const float4*)(row + lane * 8);
        const float4 v1 = *(const float4*)(row + lane * 8 + 4);
        y[0] = v0.x; y[1] = v0.y; y[2] = v0.z; y[3] = v0.w;
        y[4] = v1.x; y[5] = v1.y; y[6] = v1.z; y[7] = v1.w;
    }

    // step = 1/(2(1+16*lam)); z - step*g = (1-A) z + A y - B * DtD(z)
    const float A = 1.0f / (1.0f + 16.0f * LAMBDA);   // 2*step
    const float B = LAMBDA / (1.0f + 16.0f * LAMBDA); // 2*step*lam
    const float C = 1.0f - A;

    #pragma unroll 1
    for (int pass = 0; pass < 2; ++pass) {
        #pragma unroll
        for (int i = 0; i < 8; ++i) {
            ay[i] = A * y[i];
            // x0 = proj(y) = clip(y, 0, y) (= y since y >= 0, but do it exactly)
            float x0 = fminf(fmaxf(y[i], 0.0f), y[i]);
            x[i] = x0;
            z[i] = x0;
        }

        float t = 1.0f; // used only when !USE_TABLE

        #pragma unroll 1
        for (int it = 0; it < N_ITERS; ++it) {
            // Halo: need z[8L-2], z[8L-1] from prev lane; z[8L+8], z[8L+9] from next.
            float zm2 = __shfl_up(z[6], 1);
            float zm1 = __shfl_up(z[7], 1);
            float zp0 = __shfl_down(z[0], 1);
            float zp1 = __shfl_down(z[1], 1);

            float ze[12];
            ze[0] = zm2; ze[1] = zm1;
            #pragma unroll
            for (int i = 0; i < 8; ++i) ze[2 + i] = z[i];
            ze[10] = zp0; ze[11] = zp1;

            // dd[j] = d[8L - 2 + j] = v[k] - 2 v[k+1] + v[k+2]
            float dd[10];
            #pragma unroll
            for (int j = 0; j < 10; ++j)
                dd[j] = (ze[j] + ze[j + 2]) - 2.0f * ze[j + 1];
            // d is only defined for global k in [0, n-3]; zero outside.
            if (lane == 0)  { dd[0] = 0.0f; dd[1] = 0.0f; }
            if (lane == 63) { dd[8] = 0.0f; dd[9] = 0.0f; }

            float coef;
            if (USE_TABLE) {
                coef = coefs[it]; // uniform -> s_load, cached in L2
            } else {
                float t_new = 0.5f + __builtin_amdgcn_sqrtf(fmaf(t, t, 0.25f));
                coef = (t - 1.0f) * __builtin_amdgcn_rcpf(t_new);
                t = t_new;
            }

            #pragma unroll
            for (int i = 0; i < 8; ++i) {
                // DtD[8L+i] = d[8L+i] - 2 d[8L+i-1] + d[8L+i-2]
                float dtd = (dd[i] + dd[i + 2]) - 2.0f * dd[i + 1];
                float u = fmaf(C, z[i], ay[i]);
                u = fmaf(-B, dtd, u);
                float xn = __builtin_amdgcn_fmed3f(u, 0.0f, y[i]); // clip(u,0,y), y>=0
                z[i] = fmaf(coef, xn - x[i], xn);
                x[i] = xn;
            }
        }

        // pass 2 re-solves with y = pass-1 result
        #pragma unroll
        for (int i = 0; i < 8; ++i) y[i] = x[i];
    }

    float* orow = out + (size_t)wid * ROW_N;
    float4 o0 = make_float4(x[0], x[1], x[2], x[3]);
    float4 o1 = make_float4(x[4], x[5], x[6], x[7]);
    *(float4*)(orow + lane * 8)     = o0;
    *(float4*)(orow + lane * 8 + 4) = o1;
}

extern "C" void kernel_launch(void* const* d_in, const int* in_sizes, int n_in,
                              void* d_out, int out_size, void* d_ws, size_t ws_size,
                              hipStream_t stream) {
    const float* in = (const float*)d_in[0];
    float* out = (float*)d_out;

    const int total  = in_sizes[0];
    const int n_rows = total / ROW_N;          // 16384 for (32,512,512)
    const int waves_per_block = 4;             // 256 threads = 4 waves
    const int blocks = (n_rows + waves_per_block - 1) / waves_per_block;

    if (ws_size >= N_ITERS * sizeof(float)) {
        float* coefs = (float*)d_ws;
        coef_kernel<<<1, 64, 0, stream>>>(coefs);
        fista_kernel<true><<<blocks, 256, 0, stream>>>(in, out, coefs, n_rows);
    } else {
        fista_kernel<false><<<blocks, 256, 0, stream>>>(in, out, nullptr, n_rows);
    }
}

// Round 2
// 462.281 us; speedup vs baseline: 1.0033x; 1.0033x over previous
//
#include <hip/hip_runtime.h>
#include <math.h>

#define ROW_N 512
#define N_ITERS 100
#define LAMBDA 10.0f

// Precompute FISTA momentum coefficients coef[k] = (t_k - 1) / t_{k+1}.
__global__ void coef_kernel(float* __restrict__ coefs) {
    if (threadIdx.x == 0) {
        float t = 1.0f;
        for (int k = 0; k < N_ITERS; ++k) {
            float t_new = 0.5f * (1.0f + sqrtf(1.0f + 4.0f * t * t));
            coefs[k] = (t - 1.0f) / t_new;
            t = t_new;
        }
    }
}

// One wave (64 lanes) per row of 512; 8 contiguous elements per lane.
// Software-pipelined: iteration k's halo shuffles are issued mid-way through
// iteration k-1 (right after edge elements update), so ds_bpermute latency is
// hidden behind the middle-element updates + next interior dd computation.
template <bool USE_TABLE>
__global__ __launch_bounds__(256) void fista_kernel(
    const float* __restrict__ in, float* __restrict__ out,
    const float* __restrict__ coefs, int n_rows)
{
    const int wid  = (int)((blockIdx.x * 256u + threadIdx.x) >> 6);
    const int lane = (int)(threadIdx.x & 63u);
    if (wid >= n_rows) return;

    const float* row = in + (size_t)wid * ROW_N;

    float y[8], ay[8], x[8], z[8];
    {
        const float4 v0 = *(const float4*)(row + lane * 8);
        const float4 v1 = *(const float4*)(row + lane * 8 + 4);
        y[0] = v0.x; y[1] = v0.y; y[2] = v0.z; y[3] = v0.w;
        y[4] = v1.x; y[5] = v1.y; y[6] = v1.z; y[7] = v1.w;
    }

    // step = 1/(2(1+16*lam)); z - step*g = (1-A) z + A y - B * DtD(z)
    const float A = 1.0f / (1.0f + 16.0f * LAMBDA);   // 2*step
    const float B = LAMBDA / (1.0f + 16.0f * LAMBDA); // 2*step*lam
    const float C = 1.0f - A;

    const bool lane_lo = (lane == 0);
    const bool lane_hi = (lane == 63);

    #pragma unroll 1
    for (int pass = 0; pass < 2; ++pass) {
        #pragma unroll
        for (int i = 0; i < 8; ++i) {
            ay[i] = A * y[i];
            float x0 = fminf(fmaxf(y[i], 0.0f), y[i]);  // proj(y)
            x[i] = x0;
            z[i] = x0;
        }

        // --- pipeline prologue: halo + coef for iteration 0 ---
        float zm2 = __shfl_up(z[6], 1);
        float zm1 = __shfl_up(z[7], 1);
        float zp0 = __shfl_down(z[0], 1);
        float zp1 = __shfl_down(z[1], 1);
        float coef, t = 1.0f;
        if (USE_TABLE) coef = coefs[0];
        else           coef = 0.0f;  // (t0-1)/t1 = 0

        #pragma unroll 2
        for (int it = 0; it < N_ITERS; ++it) {
            float ze[12];
            ze[0] = zm2; ze[1] = zm1;
            #pragma unroll
            for (int i = 0; i < 8; ++i) ze[2 + i] = z[i];
            ze[10] = zp0; ze[11] = zp1;

            // dd[j] = d[8L - 2 + j] = v[k] - 2 v[k+1] + v[k+2]
            float dd[10];
            #pragma unroll
            for (int j = 0; j < 10; ++j)
                dd[j] = (ze[j] + ze[j + 2]) - 2.0f * ze[j + 1];
            if (lane_lo) { dd[0] = 0.0f; dd[1] = 0.0f; }
            if (lane_hi) { dd[8] = 0.0f; dd[9] = 0.0f; }

            // prefetch next iteration's coef (uniform s_load, latency hidden)
            float coef_next;
            if (USE_TABLE) {
                coef_next = coefs[it + 1 < N_ITERS ? it + 1 : 0];
            } else {
                float t_new = 0.5f + sqrtf(fmaf(t, t, 0.25f));
                coef_next = (t_new - 1.0f) / (0.5f + sqrtf(fmaf(t_new, t_new, 0.25f)));
                // note: coef for THIS iter was computed last iter; recurrence below
                t = t_new;
            }

            const float cf = coef;
            auto upd = [&](int i) {
                float dtd = (dd[i] + dd[i + 2]) - 2.0f * dd[i + 1];
                float u = fmaf(C, z[i], ay[i]);
                u = fmaf(-B, dtd, u);
                float xn = __builtin_amdgcn_fmed3f(u, 0.0f, y[i]); // clip(u,0,y)
                z[i] = fmaf(cf, xn - x[i], xn);
                x[i] = xn;
            };

            // 1) update edge elements (feed next iteration's halo)
            upd(0); upd(1); upd(6); upd(7);

            // 2) issue next iteration's halo shuffles on the fresh edge values
            float nzm2 = __shfl_up(z[6], 1);
            float nzm1 = __shfl_up(z[7], 1);
            float nzp0 = __shfl_down(z[0], 1);
            float nzp1 = __shfl_down(z[1], 1);

            // 3) update middle elements while the shuffles are in flight
            upd(2); upd(3); upd(4); upd(5);

            zm2 = nzm2; zm1 = nzm1; zp0 = nzp0; zp1 = nzp1;
            coef = coef_next;
        }

        // pass 2 re-solves with y = pass-1 result
        #pragma unroll
        for (int i = 0; i < 8; ++i) y[i] = x[i];
    }

    float* orow = out + (size_t)wid * ROW_N;
    float4 o0 = make_float4(x[0], x[1], x[2], x[3]);
    float4 o1 = make_float4(x[4], x[5], x[6], x[7]);
    *(float4*)(orow + lane * 8)     = o0;
    *(float4*)(orow + lane * 8 + 4) = o1;
}

extern "C" void kernel_launch(void* const* d_in, const int* in_sizes, int n_in,
                              void* d_out, int out_size, void* d_ws, size_t ws_size,
                              hipStream_t stream) {
    const float* in = (const float*)d_in[0];
    float* out = (float*)d_out;

    const int total  = in_sizes[0];
    const int n_rows = total / ROW_N;          // 16384 for (32,512,512)
    const int waves_per_block = 4;             // 256 threads = 4 waves
    const int blocks = (n_rows + waves_per_block - 1) / waves_per_block;

    if (ws_size >= N_ITERS * sizeof(float)) {
        float* coefs = (float*)d_ws;
        coef_kernel<<<1, 64, 0, stream>>>(coefs);
        fista_kernel<true><<<blocks, 256, 0, stream>>>(in, out, coefs, n_rows);
    } else {
        fista_kernel<false><<<blocks, 256, 0, stream>>>(in, out, nullptr, n_rows);
    }
}

// Round 3
// 381.637 us; speedup vs baseline: 1.2153x; 1.2113x over previous
//
#include <hip/hip_runtime.h>
#include <math.h>

#define ROW_N 512
#define N_ITERS 100
#define LAMBDA 10.0f

typedef float f2 __attribute__((ext_vector_type(2)));

__device__ __forceinline__ f2 splat(float s) { f2 r; r.x = s; r.y = s; return r; }
__device__ __forceinline__ f2 ffma(f2 a, f2 b, f2 c) {
    return __builtin_elementwise_fma(a, b, c);
}

// Precompute FISTA momentum coefficients coef[k] = (t_k - 1) / t_{k+1}.
__global__ void coef_kernel(float* __restrict__ coefs) {
    if (threadIdx.x == 0) {
        float t = 1.0f;
        for (int k = 0; k < N_ITERS; ++k) {
            float t_new = 0.5f * (1.0f + sqrtf(1.0f + 4.0f * t * t));
            coefs[k] = (t - 1.0f) / t_new;
            t = t_new;
        }
    }
}

// TWO rows per wave, packed into float2 components -> every stencil op is a
// naturally-aligned v_pk_*_f32 (no misaligned-pair construction ever).
// 8 elements/lane per row; halo via 8 shuffles/iter (4 per row), pipelined.
template <bool USE_TABLE>
__global__ __launch_bounds__(256, 4) void fista_kernel(
    const float* __restrict__ in, float* __restrict__ out,
    const float* __restrict__ coefs, int n_rows)
{
    const int pid  = (int)((blockIdx.x * 256u + threadIdx.x) >> 6); // row-pair id
    const int lane = (int)(threadIdx.x & 63u);
    const int n_pairs = (n_rows + 1) >> 1;
    if (pid >= n_pairs) return;

    const int r0 = pid * 2;
    const int r1 = (r0 + 1 < n_rows) ? r0 + 1 : r0;
    const float* rowA = in + (size_t)r0 * ROW_N + lane * 8;
    const float* rowB = in + (size_t)r1 * ROW_N + lane * 8;

    f2 y[8], ay[8], x[8], z[8];
    {
        const float4 a0 = *(const float4*)(rowA);
        const float4 a1 = *(const float4*)(rowA + 4);
        const float4 b0 = *(const float4*)(rowB);
        const float4 b1 = *(const float4*)(rowB + 4);
        y[0].x = a0.x; y[1].x = a0.y; y[2].x = a0.z; y[3].x = a0.w;
        y[4].x = a1.x; y[5].x = a1.y; y[6].x = a1.z; y[7].x = a1.w;
        y[0].y = b0.x; y[1].y = b0.y; y[2].y = b0.z; y[3].y = b0.w;
        y[4].y = b1.x; y[5].y = b1.y; y[6].y = b1.z; y[7].y = b1.w;
    }

    // step = 1/(2(1+16*lam)); z - step*g = (1-A) z + A y - B * DtD(z)
    const float A = 1.0f / (1.0f + 16.0f * LAMBDA);
    const float B = LAMBDA / (1.0f + 16.0f * LAMBDA);
    const float C = 1.0f - A;
    const f2 Cv = splat(C), Av = splat(A), Bn = splat(-B), M2 = splat(-2.0f);

    const bool lane_lo = (lane == 0);
    const bool lane_hi = (lane == 63);

    #pragma unroll 1
    for (int pass = 0; pass < 2; ++pass) {
        #pragma unroll
        for (int i = 0; i < 8; ++i) {
            ay[i] = Av * y[i];
            f2 x0;  // proj(y) = clip(y,0,y)
            x0.x = fminf(fmaxf(y[i].x, 0.0f), y[i].x);
            x0.y = fminf(fmaxf(y[i].y, 0.0f), y[i].y);
            x[i] = x0;
            z[i] = x0;
        }

        // pipeline prologue: halo + coef for iteration 0
        f2 zm2, zm1, zp0, zp1;
        zm2.x = __shfl_up(z[6].x, 1);   zm2.y = __shfl_up(z[6].y, 1);
        zm1.x = __shfl_up(z[7].x, 1);   zm1.y = __shfl_up(z[7].y, 1);
        zp0.x = __shfl_down(z[0].x, 1); zp0.y = __shfl_down(z[0].y, 1);
        zp1.x = __shfl_down(z[1].x, 1); zp1.y = __shfl_down(z[1].y, 1);
        float coef, t = 1.0f;
        if (USE_TABLE) coef = coefs[0];
        else           coef = 0.0f;   // (t0-1)/t1 = 0

        #pragma unroll 2
        for (int it = 0; it < N_ITERS; ++it) {
            // dd[j] = d[8L-2+j] = v - 2*w + u (second difference), f2-packed
            f2 dd[10];
            dd[0] = ffma(M2, zm1, zm2 + z[0]);
            dd[1] = ffma(M2, z[0], zm1 + z[1]);
            #pragma unroll
            for (int j = 2; j < 8; ++j)
                dd[j] = ffma(M2, z[j - 1], z[j - 2] + z[j]);
            dd[8] = ffma(M2, z[7], z[6] + zp0);
            dd[9] = ffma(M2, zp0, z[7] + zp1);
            if (lane_lo) { dd[0] = splat(0.0f); dd[1] = splat(0.0f); }
            if (lane_hi) { dd[8] = splat(0.0f); dd[9] = splat(0.0f); }

            // prefetch next iteration's coef (uniform s_load)
            float coef_next;
            if (USE_TABLE) {
                coef_next = coefs[it + 1 < N_ITERS ? it + 1 : 0];
            } else {
                float t_new = 0.5f + sqrtf(fmaf(t, t, 0.25f));
                coef_next = (t_new - 1.0f) / (0.5f + sqrtf(fmaf(t_new, t_new, 0.25f)));
                t = t_new;
            }

            const f2 cfv = splat(coef);
            auto upd = [&](int i) {
                f2 dtd = ffma(M2, dd[i + 1], dd[i] + dd[i + 2]);
                f2 u = ffma(Cv, z[i], ay[i]);
                u = ffma(Bn, dtd, u);
                f2 xn;
                xn.x = __builtin_amdgcn_fmed3f(u.x, 0.0f, y[i].x); // clip(u,0,y)
                xn.y = __builtin_amdgcn_fmed3f(u.y, 0.0f, y[i].y);
                z[i] = ffma(cfv, xn - x[i], xn);
                x[i] = xn;
            };

            // 1) edge elements first (they feed next iteration's halo)
            upd(0); upd(1); upd(6); upd(7);

            // 2) issue next halo shuffles on fresh edge values
            f2 nzm2, nzm1, nzp0, nzp1;
            nzm2.x = __shfl_up(z[6].x, 1);   nzm2.y = __shfl_up(z[6].y, 1);
            nzm1.x = __shfl_up(z[7].x, 1);   nzm1.y = __shfl_up(z[7].y, 1);
            nzp0.x = __shfl_down(z[0].x, 1); nzp0.y = __shfl_down(z[0].y, 1);
            nzp1.x = __shfl_down(z[1].x, 1); nzp1.y = __shfl_down(z[1].y, 1);

            // 3) middle elements while shuffles are in flight
            upd(2); upd(3); upd(4); upd(5);

            zm2 = nzm2; zm1 = nzm1; zp0 = nzp0; zp1 = nzp1;
            coef = coef_next;
        }

        #pragma unroll
        for (int i = 0; i < 8; ++i) y[i] = x[i];  // pass 2: y = pass-1 result
    }

    float* orowA = out + (size_t)r0 * ROW_N + lane * 8;
    *(float4*)(orowA)     = make_float4(x[0].x, x[1].x, x[2].x, x[3].x);
    *(float4*)(orowA + 4) = make_float4(x[4].x, x[5].x, x[6].x, x[7].x);
    if (r1 > r0) {
        float* orowB = out + (size_t)r1 * ROW_N + lane * 8;
        *(float4*)(orowB)     = make_float4(x[0].y, x[1].y, x[2].y, x[3].y);
        *(float4*)(orowB + 4) = make_float4(x[4].y, x[5].y, x[6].y, x[7].y);
    }
}

extern "C" void kernel_launch(void* const* d_in, const int* in_sizes, int n_in,
                              void* d_out, int out_size, void* d_ws, size_t ws_size,
                              hipStream_t stream) {
    const float* in = (const float*)d_in[0];
    float* out = (float*)d_out;

    const int total   = in_sizes[0];
    const int n_rows  = total / ROW_N;         // 16384 for (32,512,512)
    const int n_pairs = (n_rows + 1) >> 1;     // 2 rows per wave
    const int waves_per_block = 4;             // 256 threads
    const int blocks = (n_pairs + waves_per_block - 1) / waves_per_block;

    if (ws_size >= N_ITERS * sizeof(float)) {
        float* coefs = (float*)d_ws;
        coef_kernel<<<1, 64, 0, stream>>>(coefs);
        fista_kernel<true><<<blocks, 256, 0, stream>>>(in, out, coefs, n_rows);
    } else {
        fista_kernel<false><<<blocks, 256, 0, stream>>>(in, out, nullptr, n_rows);
    }
}